// Round 2
// baseline (307.394 us; speedup 1.0000x reference)
//
#include <hip/hip_runtime.h>
#include <hip/hip_bf16.h>

// ---------- problem sizes (fixed by setup_inputs) ----------
#define BB 8
#define SS 4096
#define DD 256      // d_input
#define NN 256      // d_state
#define OO 256      // d_output
#define MM (BB*SS)  // 32768 rows
#define CHUNK 64
#define NCH (SS/CHUNK)  // 64 chunks

// ---------- ws layout ----------
// float region first, then bf16 arrays
#define WS_AR 0
#define WS_AI 256
#define WS_SR 512
#define WS_SI 768
#define WS_PR 1024
#define WS_PI 1280
#define WS_FINR 1536
#define WS_FINI (WS_FINR + BB*NCH*NN)
#define WS_CARR (WS_FINI + BB*NCH*NN)
#define WS_CARI (WS_CARR + BB*NCH*NN)
#define WS_FLOATS (WS_CARI + BB*NCH*NN)
#define WS_V_BYTE  ((size_t)WS_FLOATS * 4)
#define WS_HR_BYTE (WS_V_BYTE  + (size_t)MM*NN*2)
#define WS_HI_BYTE (WS_HR_BYTE + (size_t)MM*NN*2)

typedef __bf16 bf16_t;
typedef bf16_t bf16x8 __attribute__((ext_vector_type(8)));
typedef float  f32x4  __attribute__((ext_vector_type(4)));
typedef unsigned int u32x4 __attribute__((ext_vector_type(4)));

__device__ inline bf16_t f2b(float f) {
    __hip_bfloat16 h = __float2bfloat16(f);
    return __builtin_bit_cast(bf16_t, h);
}

__device__ inline bf16x8 cvt8(f32x4 a, f32x4 b) {
    bf16x8 o;
    o[0] = f2b(a[0]); o[1] = f2b(a[1]); o[2] = f2b(a[2]); o[3] = f2b(a[3]);
    o[4] = f2b(b[0]); o[5] = f2b(b[1]); o[6] = f2b(b[2]); o[7] = f2b(b[3]);
    return o;
}

// ---------- per-state constants: A_bar, s=dt/denom, P=A^CHUNK ----------
__global__ void k_consts(const float* __restrict__ llr,
                         const float* __restrict__ li,
                         const float* __restrict__ ldt,
                         float* __restrict__ ws) {
    int n = threadIdx.x;
    float lr = -expf(llr[n]);            // Re(Lambda)
    float im = li[n];                    // Im(Lambda)
    float dt = expf(ldt[n]);
    dt = fminf(fmaxf(dt, 0.005f), 0.1f);
    float hr = 0.5f * dt * lr, hi = 0.5f * dt * im;
    float nr = 1.f + hr, ni = hi;        // 1 + dt/2*Lambda
    float dr = 1.f - hr, di = -hi;       // 1 - dt/2*Lambda
    float inv = 1.f / (dr*dr + di*di);
    float Ar = (nr*dr + ni*di) * inv;
    float Ai = (ni*dr - nr*di) * inv;
    float sr = dt * dr * inv;
    float si = -dt * di * inv;
    float pr = Ar, pi = Ai;
    #pragma unroll
    for (int i = 0; i < 6; ++i) {        // A^64 via repeated squaring
        float t = pr*pr - pi*pi; pi = 2.f*pr*pi; pr = t;
    }
    ws[WS_AR+n]=Ar; ws[WS_AI+n]=Ai; ws[WS_SR+n]=sr;
    ws[WS_SI+n]=si; ws[WS_PR+n]=pr; ws[WS_PI+n]=pi;
}

// ---------- GEMM1: v[m,n] = sum_d x[m,d]*B[n,d]  (fp32 in, bf16 MFMA) ------
// A frag: A[m=lane&15][k=q*8+j]; B frag: B[n=lane&15][k=q*8+j]
// C/D: col=lane&15, row=q*4+reg  (verified layouts, m89/m91)
__global__ __launch_bounds__(256) void k_gemm1(const float* __restrict__ X,
                                               const float* __restrict__ Bm,
                                               __hip_bfloat16* __restrict__ V) {
    int tid = threadIdx.x, wave = tid >> 6, lane = tid & 63;
    int q = lane >> 4, r = lane & 15;
    int m0 = (blockIdx.y * 4 + wave) * 16;
    int n0 = blockIdx.x * 64;
    f32x4 acc[4] = {};
    const f32x4* Xv = (const f32x4*)X;      // row stride 256 f32 = 64 f32x4
    const f32x4* Bv = (const f32x4*)Bm;
    #pragma unroll
    for (int kk = 0; kk < 8; ++kk) {
        int ko = kk * 8 + q * 2;            // f32x4 index of k = kk*32 + q*8
        f32x4 a0 = Xv[(size_t)(m0 + r) * 64 + ko];
        f32x4 a1 = Xv[(size_t)(m0 + r) * 64 + ko + 1];
        bf16x8 av = cvt8(a0, a1);
        #pragma unroll
        for (int t = 0; t < 4; ++t) {
            f32x4 b0 = Bv[(size_t)(n0 + t*16 + r) * 64 + ko];
            f32x4 b1 = Bv[(size_t)(n0 + t*16 + r) * 64 + ko + 1];
            acc[t] = __builtin_amdgcn_mfma_f32_16x16x32_bf16(
                av, cvt8(b0, b1), acc[t], 0, 0, 0);
        }
    }
    #pragma unroll
    for (int t = 0; t < 4; ++t)
        #pragma unroll
        for (int reg = 0; reg < 4; ++reg)
            V[(size_t)(m0 + q*4 + reg) * NN + n0 + t*16 + r] =
                __float2bfloat16(acc[t][reg]);
}

// ---------- scan pass 1: chunk-local finals (zero init) ----------
__global__ __launch_bounds__(256) void k_scan1(const __hip_bfloat16* __restrict__ V,
                                               const float* __restrict__ cst,
                                               float* __restrict__ finr,
                                               float* __restrict__ fini) {
    int n = threadIdx.x, c = blockIdx.x, b = blockIdx.y;
    float Ar = cst[WS_AR+n], Ai = cst[WS_AI+n];
    float sr = cst[WS_SR+n], si = cst[WS_SI+n];
    size_t idx = ((size_t)(b * SS + c * CHUNK)) * NN + n;
    float hr = 0.f, hi = 0.f;
    #pragma unroll 8
    for (int i = 0; i < CHUNK; ++i) {
        float vv = __bfloat162float(V[idx]);
        float tr = fmaf(Ar, hr, fmaf(-Ai, hi, sr * vv));
        float ti = fmaf(Ar, hi, fmaf( Ai, hr, si * vv));
        hr = tr; hi = ti; idx += NN;
    }
    int f = (b * NCH + c) * NN + n;
    finr[f] = hr; fini[f] = hi;
}

// ---------- scan pass 2: carry scan across chunks ----------
__global__ __launch_bounds__(256) void k_scan2(const float* __restrict__ cst,
                                               const float* __restrict__ finr,
                                               const float* __restrict__ fini,
                                               float* __restrict__ carr,
                                               float* __restrict__ cari) {
    int n = threadIdx.x, b = blockIdx.x;
    float Pr = cst[WS_PR+n], Pi = cst[WS_PI+n];
    float sr = 0.f, si = 0.f;
    #pragma unroll 8
    for (int c = 0; c < NCH; ++c) {
        int f = (b * NCH + c) * NN + n;
        carr[f] = sr; cari[f] = si;
        float fr = finr[f], fi = fini[f];
        float tr = fmaf(Pr, sr, fmaf(-Pi, si, fr));
        float ti = fmaf(Pr, si, fmaf( Pi, sr, fi));
        sr = tr; si = ti;
    }
}

// ---------- scan pass 3: replay with carries, emit h (bf16) ----------
__global__ __launch_bounds__(256) void k_scan3(const __hip_bfloat16* __restrict__ V,
                                               const float* __restrict__ cst,
                                               const float* __restrict__ carr,
                                               const float* __restrict__ cari,
                                               __hip_bfloat16* __restrict__ HR,
                                               __hip_bfloat16* __restrict__ HI) {
    int n = threadIdx.x, c = blockIdx.x, b = blockIdx.y;
    float Ar = cst[WS_AR+n], Ai = cst[WS_AI+n];
    float sr = cst[WS_SR+n], si = cst[WS_SI+n];
    int f = (b * NCH + c) * NN + n;
    float hr = carr[f], hi = cari[f];
    size_t idx = ((size_t)(b * SS + c * CHUNK)) * NN + n;
    #pragma unroll 8
    for (int i = 0; i < CHUNK; ++i) {
        float vv = __bfloat162float(V[idx]);
        float tr = fmaf(Ar, hr, fmaf(-Ai, hi, sr * vv));
        float ti = fmaf(Ar, hi, fmaf( Ai, hr, si * vv));
        hr = tr; hi = ti;
        HR[idx] = __float2bfloat16(hr);
        HI[idx] = __float2bfloat16(hi);
        idx += NN;
    }
}

// ---------- GEMM2: out[m,o] = sum_n hr[m,n]*Cr[o,n] - hi[m,n]*Ci[o,n] ------
__global__ __launch_bounds__(256) void k_gemm2(const u32x4* __restrict__ HR,
                                               const u32x4* __restrict__ HI,
                                               const float* __restrict__ Cr,
                                               const float* __restrict__ Ci,
                                               float* __restrict__ out) {
    int tid = threadIdx.x, wave = tid >> 6, lane = tid & 63;
    int q = lane >> 4, r = lane & 15;
    int m0 = (blockIdx.y * 4 + wave) * 16;
    int o0 = blockIdx.x * 64;
    f32x4 acc[4] = {}, acc2[4] = {};
    const u32x4* hrrow = HR + (size_t)(m0 + r) * 32 + q;  // bf16 row = 32 u32x4
    const u32x4* hirow = HI + (size_t)(m0 + r) * 32 + q;
    const f32x4* Crv = (const f32x4*)Cr;                  // fp32 row = 64 f32x4
    const f32x4* Civ = (const f32x4*)Ci;
    #pragma unroll
    for (int kk = 0; kk < 8; ++kk) {
        u32x4 au = hrrow[kk * 4];
        u32x4 bu = hirow[kk * 4];
        bf16x8 ar = __builtin_bit_cast(bf16x8, au);
        bf16x8 ai = __builtin_bit_cast(bf16x8, bu);
        int ko = kk * 8 + q * 2;
        #pragma unroll
        for (int t = 0; t < 4; ++t) {
            f32x4 cr0 = Crv[(size_t)(o0 + t*16 + r) * 64 + ko];
            f32x4 cr1 = Crv[(size_t)(o0 + t*16 + r) * 64 + ko + 1];
            f32x4 ci0 = Civ[(size_t)(o0 + t*16 + r) * 64 + ko];
            f32x4 ci1 = Civ[(size_t)(o0 + t*16 + r) * 64 + ko + 1];
            acc[t]  = __builtin_amdgcn_mfma_f32_16x16x32_bf16(
                ar, cvt8(cr0, cr1), acc[t], 0, 0, 0);
            acc2[t] = __builtin_amdgcn_mfma_f32_16x16x32_bf16(
                ai, cvt8(ci0, ci1), acc2[t], 0, 0, 0);
        }
    }
    #pragma unroll
    for (int t = 0; t < 4; ++t)
        #pragma unroll
        for (int reg = 0; reg < 4; ++reg)
            out[(size_t)(m0 + q*4 + reg) * OO + o0 + t*16 + r] =
                acc[t][reg] - acc2[t][reg];
}

extern "C" void kernel_launch(void* const* d_in, const int* in_sizes, int n_in,
                              void* d_out, int out_size, void* d_ws, size_t ws_size,
                              hipStream_t stream) {
    const float* x   = (const float*)d_in[0];
    const float* llr = (const float*)d_in[1];
    const float* li  = (const float*)d_in[2];
    const float* ldt = (const float*)d_in[3];
    const float* Bm  = (const float*)d_in[4];
    const float* Cr  = (const float*)d_in[5];
    const float* Ci  = (const float*)d_in[6];

    float* wsf = (float*)d_ws;
    char*  wsb = (char*)d_ws;
    __hip_bfloat16* V  = (__hip_bfloat16*)(wsb + WS_V_BYTE);
    __hip_bfloat16* HR = (__hip_bfloat16*)(wsb + WS_HR_BYTE);
    __hip_bfloat16* HI = (__hip_bfloat16*)(wsb + WS_HI_BYTE);

    k_consts<<<1, 256, 0, stream>>>(llr, li, ldt, wsf);
    k_gemm1<<<dim3(NN/64, MM/64), 256, 0, stream>>>(x, Bm, V);
    k_scan1<<<dim3(NCH, BB), 256, 0, stream>>>(V, wsf,
        wsf + WS_FINR, wsf + WS_FINI);
    k_scan2<<<BB, 256, 0, stream>>>(wsf,
        wsf + WS_FINR, wsf + WS_FINI, wsf + WS_CARR, wsf + WS_CARI);
    k_scan3<<<dim3(NCH, BB), 256, 0, stream>>>(V, wsf,
        wsf + WS_CARR, wsf + WS_CARI, HR, HI);
    k_gemm2<<<dim3(OO/64, MM/64), 256, 0, stream>>>(
        (const u32x4*)HR, (const u32x4*)HI, Cr, Ci, (float*)d_out);
}

// Round 3
// 157.884 us; speedup vs baseline: 1.9470x; 1.9470x over previous
//
#include <hip/hip_runtime.h>
#include <hip/hip_bf16.h>

// ---------- problem sizes (fixed by setup_inputs) ----------
#define BB 8
#define SS 4096
#define NN 256      // d_state (= d_input = d_output)
#define OO 256
#define MM (BB*SS)  // 32768 rows
#define CHUNK 32
#define NCH (SS/CHUNK)  // 128 chunks

// ---------- ws layout ----------
#define WS_AR 0
#define WS_AI 256
#define WS_SR 512
#define WS_SI 768
#define WS_PR 1024
#define WS_PI 1280
#define WS_FINR 1536
#define WS_FINI (WS_FINR + BB*NCH*NN)
#define WS_CARR (WS_FINI + BB*NCH*NN)
#define WS_CARI (WS_CARR + BB*NCH*NN)
#define WS_FLOATS (WS_CARI + BB*NCH*NN)
#define WS_V_BYTE  ((size_t)WS_FLOATS * 4)
#define WS_HR_BYTE (WS_V_BYTE  + (size_t)MM*NN*2)
#define WS_HI_BYTE (WS_HR_BYTE + (size_t)MM*NN*2)

typedef __bf16 bf16_t;
typedef bf16_t bf16x8 __attribute__((ext_vector_type(8)));
typedef float  f32x4  __attribute__((ext_vector_type(4)));
typedef unsigned int u32x4 __attribute__((ext_vector_type(4)));

__device__ inline bf16_t f2b(float f) {
    __hip_bfloat16 h = __float2bfloat16(f);
    return __builtin_bit_cast(bf16_t, h);
}
__device__ inline bf16x8 cvt8(f32x4 a, f32x4 b) {
    bf16x8 o;
    o[0]=f2b(a[0]); o[1]=f2b(a[1]); o[2]=f2b(a[2]); o[3]=f2b(a[3]);
    o[4]=f2b(b[0]); o[5]=f2b(b[1]); o[6]=f2b(b[2]); o[7]=f2b(b[3]);
    return o;
}

// ---------- per-state constants ----------
__global__ void k_consts(const float* __restrict__ llr,
                         const float* __restrict__ li,
                         const float* __restrict__ ldt,
                         float* __restrict__ ws) {
    int n = threadIdx.x;
    float lr = -expf(llr[n]);
    float im = li[n];
    float dt = expf(ldt[n]);
    dt = fminf(fmaxf(dt, 0.005f), 0.1f);
    float hr = 0.5f * dt * lr, hi = 0.5f * dt * im;
    float nr = 1.f + hr, ni = hi;
    float dr = 1.f - hr, di = -hi;
    float inv = 1.f / (dr*dr + di*di);
    float Ar = (nr*dr + ni*di) * inv;
    float Ai = (ni*dr - nr*di) * inv;
    float sr = dt * dr * inv;
    float si = -dt * di * inv;
    float pr = Ar, pi = Ai;
    #pragma unroll
    for (int i = 0; i < 5; ++i) {        // A^32 (CHUNK=32)
        float t = pr*pr - pi*pi; pi = 2.f*pr*pi; pr = t;
    }
    ws[WS_AR+n]=Ar; ws[WS_AI+n]=Ai; ws[WS_SR+n]=sr;
    ws[WS_SI+n]=si; ws[WS_PR+n]=pr; ws[WS_PI+n]=pi;
}

// ============================================================
// Tiled GEMM1: V[m,n] = sum_k x[m,k]*Bw[n,k]   (128x128 tile)
// LDS layout: fragment-swizzled — slot f = tile*64+lane, 16B each,
// tile = mt*2+kb; lane reads its own 16B via ds_read_b128 (no conflicts).
// Frag maps (verified m89/m91): A[m=lane&15][k=(lane>>4)*8+j], same for B(n);
// C/D: col=lane&15, row=(lane>>4)*4+reg.
// ============================================================
__global__ __launch_bounds__(256) void k_gemm1(const float* __restrict__ X,
                                               const float* __restrict__ Bw,
                                               __hip_bfloat16* __restrict__ V) {
    __shared__ bf16x8 lds_a[1024];   // 16KB
    __shared__ bf16x8 lds_b[1024];   // 16KB
    int t = threadIdx.x;
    int w = t >> 6, lane = t & 63;
    int q = lane >> 4, r = lane & 15;
    int Mblk = blockIdx.x;           // 0..255 (M-major for L3 reuse of X)
    int Nblk = blockIdx.y;           // 0..1
    int wmt = (w & 1) * 4;           // wave's first m-tile (of 8)
    int wnt = (w >> 1) * 4;          // wave's first n-tile
    f32x4 acc[4][4] = {};

    for (int kk = 0; kk < 4; ++kk) {
        int k0 = kk * 64;
        #pragma unroll
        for (int s = 0; s < 4; ++s) {
            int f    = s * 256 + t;
            int tile = f >> 6;            // 0..15
            int ls   = f & 63;
            int mt   = tile >> 1, kb = tile & 1;
            int qq   = ls >> 4, rr = ls & 15;
            int col  = k0 + kb * 32 + qq * 8;
            const f32x4* pa = (const f32x4*)(X  + (size_t)(Mblk*128 + mt*16 + rr) * 256 + col);
            const f32x4* pb = (const f32x4*)(Bw + (size_t)(Nblk*128 + mt*16 + rr) * 256 + col);
            lds_a[f] = cvt8(pa[0], pa[1]);
            lds_b[f] = cvt8(pb[0], pb[1]);
        }
        __syncthreads();
        #pragma unroll
        for (int kb = 0; kb < 2; ++kb) {
            bf16x8 af[4], bfr[4];
            #pragma unroll
            for (int i = 0; i < 4; ++i) {
                af[i]  = lds_a[((wmt + i)*2 + kb)*64 + lane];
                bfr[i] = lds_b[((wnt + i)*2 + kb)*64 + lane];
            }
            #pragma unroll
            for (int mt = 0; mt < 4; ++mt)
                #pragma unroll
                for (int nt = 0; nt < 4; ++nt)
                    acc[mt][nt] = __builtin_amdgcn_mfma_f32_16x16x32_bf16(
                        af[mt], bfr[nt], acc[mt][nt], 0, 0, 0);
        }
        __syncthreads();
    }
    #pragma unroll
    for (int mt = 0; mt < 4; ++mt) {
        int row = Mblk*128 + (wmt + mt)*16 + q*4;
        #pragma unroll
        for (int reg = 0; reg < 4; ++reg)
            #pragma unroll
            for (int nt = 0; nt < 4; ++nt)
                V[(size_t)(row + reg) * NN + Nblk*128 + (wnt + nt)*16 + r] =
                    __float2bfloat16(acc[mt][nt][reg]);
    }
}

// ============================================================
// Tiled GEMM2: out[m,o] = sum_n HR[m,n]Cr[o,n] - HI[m,n]Ci[o,n]
// as ONE gemm with virtual K=512: A=[HR|HI] bf16, B=[Cr|-Ci] fp32->bf16
// ============================================================
__global__ __launch_bounds__(256) void k_gemm2(const __hip_bfloat16* __restrict__ HR,
                                               const __hip_bfloat16* __restrict__ HI,
                                               const float* __restrict__ Cr,
                                               const float* __restrict__ Ci,
                                               float* __restrict__ out) {
    __shared__ bf16x8 lds_a[1024];
    __shared__ bf16x8 lds_b[1024];
    int t = threadIdx.x;
    int w = t >> 6, lane = t & 63;
    int q = lane >> 4, r = lane & 15;
    int Mblk = blockIdx.x;
    int Nblk = blockIdx.y;
    int wmt = (w & 1) * 4;
    int wnt = (w >> 1) * 4;
    f32x4 acc[4][4] = {};

    for (int kk = 0; kk < 8; ++kk) {
        const __hip_bfloat16* Asrc = (kk < 4) ? HR : HI;
        const float*          Bsrc = (kk < 4) ? Cr : Ci;
        float bsign = (kk < 4) ? 1.f : -1.f;
        int k0 = (kk & 3) * 64;
        #pragma unroll
        for (int s = 0; s < 4; ++s) {
            int f    = s * 256 + t;
            int tile = f >> 6;
            int ls   = f & 63;
            int mt   = tile >> 1, kb = tile & 1;
            int qq   = ls >> 4, rr = ls & 15;
            int col  = k0 + kb * 32 + qq * 8;
            const u32x4* pa = (const u32x4*)(Asrc + (size_t)(Mblk*128 + mt*16 + rr) * 256 + col);
            lds_a[f] = __builtin_bit_cast(bf16x8, pa[0]);
            const f32x4* pb = (const f32x4*)(Bsrc + (size_t)(Nblk*128 + mt*16 + rr) * 256 + col);
            lds_b[f] = cvt8(pb[0] * bsign, pb[1] * bsign);
        }
        __syncthreads();
        #pragma unroll
        for (int kb = 0; kb < 2; ++kb) {
            bf16x8 af[4], bfr[4];
            #pragma unroll
            for (int i = 0; i < 4; ++i) {
                af[i]  = lds_a[((wmt + i)*2 + kb)*64 + lane];
                bfr[i] = lds_b[((wnt + i)*2 + kb)*64 + lane];
            }
            #pragma unroll
            for (int mt = 0; mt < 4; ++mt)
                #pragma unroll
                for (int nt = 0; nt < 4; ++nt)
                    acc[mt][nt] = __builtin_amdgcn_mfma_f32_16x16x32_bf16(
                        af[mt], bfr[nt], acc[mt][nt], 0, 0, 0);
        }
        __syncthreads();
    }
    #pragma unroll
    for (int mt = 0; mt < 4; ++mt) {
        int row = Mblk*128 + (wmt + mt)*16 + q*4;
        #pragma unroll
        for (int reg = 0; reg < 4; ++reg)
            #pragma unroll
            for (int nt = 0; nt < 4; ++nt)
                out[(size_t)(row + reg) * OO + Nblk*128 + (wnt + nt)*16 + r] =
                    acc[mt][nt][reg];
    }
}

// ---------- scan pass 1: chunk-local finals ----------
__global__ __launch_bounds__(256) void k_scan1(const __hip_bfloat16* __restrict__ V,
                                               const float* __restrict__ cst,
                                               float* __restrict__ finr,
                                               float* __restrict__ fini) {
    int n = threadIdx.x, c = blockIdx.x, b = blockIdx.y;
    float Ar = cst[WS_AR+n], Ai = cst[WS_AI+n];
    float sr = cst[WS_SR+n], si = cst[WS_SI+n];
    size_t idx = ((size_t)(b * SS + c * CHUNK)) * NN + n;
    float hr = 0.f, hi = 0.f;
    #pragma unroll 8
    for (int i = 0; i < CHUNK; ++i) {
        float vv = __bfloat162float(V[idx]);
        float tr = fmaf(Ar, hr, fmaf(-Ai, hi, sr * vv));
        float ti = fmaf(Ar, hi, fmaf( Ai, hr, si * vv));
        hr = tr; hi = ti; idx += NN;
    }
    int f = (b * NCH + c) * NN + n;
    finr[f] = hr; fini[f] = hi;
}

// ---------- scan pass 2: carry scan across chunks ----------
__global__ __launch_bounds__(256) void k_scan2(const float* __restrict__ cst,
                                               const float* __restrict__ finr,
                                               const float* __restrict__ fini,
                                               float* __restrict__ carr,
                                               float* __restrict__ cari) {
    int n = threadIdx.x, b = blockIdx.x;
    float Pr = cst[WS_PR+n], Pi = cst[WS_PI+n];
    float sr = 0.f, si = 0.f;
    #pragma unroll 8
    for (int c = 0; c < NCH; ++c) {
        int f = (b * NCH + c) * NN + n;
        carr[f] = sr; cari[f] = si;
        float fr = finr[f], fi = fini[f];
        float tr = fmaf(Pr, sr, fmaf(-Pi, si, fr));
        float ti = fmaf(Pr, si, fmaf( Pi, sr, fi));
        sr = tr; si = ti;
    }
}

// ---------- scan pass 3: replay with carries, emit h ----------
__global__ __launch_bounds__(256) void k_scan3(const __hip_bfloat16* __restrict__ V,
                                               const float* __restrict__ cst,
                                               const float* __restrict__ carr,
                                               const float* __restrict__ cari,
                                               __hip_bfloat16* __restrict__ HR,
                                               __hip_bfloat16* __restrict__ HI) {
    int n = threadIdx.x, c = blockIdx.x, b = blockIdx.y;
    float Ar = cst[WS_AR+n], Ai = cst[WS_AI+n];
    float sr = cst[WS_SR+n], si = cst[WS_SI+n];
    int f = (b * NCH + c) * NN + n;
    float hr = carr[f], hi = cari[f];
    size_t idx = ((size_t)(b * SS + c * CHUNK)) * NN + n;
    #pragma unroll 8
    for (int i = 0; i < CHUNK; ++i) {
        float vv = __bfloat162float(V[idx]);
        float tr = fmaf(Ar, hr, fmaf(-Ai, hi, sr * vv));
        float ti = fmaf(Ar, hi, fmaf( Ai, hr, si * vv));
        hr = tr; hi = ti;
        HR[idx] = __float2bfloat16(hr);
        HI[idx] = __float2bfloat16(hi);
        idx += NN;
    }
}

extern "C" void kernel_launch(void* const* d_in, const int* in_sizes, int n_in,
                              void* d_out, int out_size, void* d_ws, size_t ws_size,
                              hipStream_t stream) {
    const float* x   = (const float*)d_in[0];
    const float* llr = (const float*)d_in[1];
    const float* li  = (const float*)d_in[2];
    const float* ldt = (const float*)d_in[3];
    const float* Bw  = (const float*)d_in[4];
    const float* Cr  = (const float*)d_in[5];
    const float* Ci  = (const float*)d_in[6];

    float* wsf = (float*)d_ws;
    char*  wsb = (char*)d_ws;
    __hip_bfloat16* V  = (__hip_bfloat16*)(wsb + WS_V_BYTE);
    __hip_bfloat16* HR = (__hip_bfloat16*)(wsb + WS_HR_BYTE);
    __hip_bfloat16* HI = (__hip_bfloat16*)(wsb + WS_HI_BYTE);

    k_consts<<<1, 256, 0, stream>>>(llr, li, ldt, wsf);
    k_gemm1<<<dim3(MM/128, NN/128), 256, 0, stream>>>(x, Bw, V);
    k_scan1<<<dim3(NCH, BB), 256, 0, stream>>>(V, wsf,
        wsf + WS_FINR, wsf + WS_FINI);
    k_scan2<<<BB, 256, 0, stream>>>(wsf,
        wsf + WS_FINR, wsf + WS_FINI, wsf + WS_CARR, wsf + WS_CARI);
    k_scan3<<<dim3(NCH, BB), 256, 0, stream>>>(V, wsf,
        wsf + WS_CARR, wsf + WS_CARI, HR, HI);
    k_gemm2<<<dim3(MM/128, OO/128), 256, 0, stream>>>(
        HR, HI, Cr, Ci, (float*)d_out);
}

// Round 4
// 138.460 us; speedup vs baseline: 2.2201x; 1.1403x over previous
//
#include <hip/hip_runtime.h>
#include <hip/hip_bf16.h>

// ---------- problem sizes (fixed by setup_inputs) ----------
#define BB 8
#define SS 4096
#define NN 256      // d_state = d_input = d_output
#define MM (BB*SS)  // 32768 rows
#define CHUNK 32
#define NCH (SS/CHUNK)  // 128 chunks per batch

// ---------- ws layout ----------
#define WS_FINR 0
#define WS_FINI (BB*NCH*NN)
#define WS_CARR (2*BB*NCH*NN)
#define WS_CARI (3*BB*NCH*NN)
#define WS_FLOATS (4*BB*NCH*NN)
#define WS_V_BYTE  ((size_t)WS_FLOATS * 4)
#define WS_CP_BYTE (WS_V_BYTE + (size_t)MM*NN*2)   // Cpack: 16384 * 16B = 256KB

typedef __bf16 bf16_t;
typedef bf16_t bf16x8 __attribute__((ext_vector_type(8)));
typedef float  f32x4  __attribute__((ext_vector_type(4)));
typedef unsigned int u32x4 __attribute__((ext_vector_type(4)));

__device__ inline bf16_t f2b(float f) {
    __hip_bfloat16 h = __float2bfloat16(f);
    return __builtin_bit_cast(bf16_t, h);
}
__device__ inline bf16x8 cvt8(f32x4 a, f32x4 b) {
    bf16x8 o;
    o[0]=f2b(a[0]); o[1]=f2b(a[1]); o[2]=f2b(a[2]); o[3]=f2b(a[3]);
    o[4]=f2b(b[0]); o[5]=f2b(b[1]); o[6]=f2b(b[2]); o[7]=f2b(b[3]);
    return o;
}

// bilinear-discretization constants for state n (recomputed per block; ~30 VALU)
__device__ inline void ssm_consts(const float* llr, const float* li, const float* ldt,
                                  int n, float& Ar, float& Ai, float& sr, float& si) {
    float lr = -expf(llr[n]);
    float im = li[n];
    float dt = expf(ldt[n]);
    dt = fminf(fmaxf(dt, 0.005f), 0.1f);
    float hr = 0.5f * dt * lr, hi = 0.5f * dt * im;
    float dr = 1.f - hr, di = -hi;
    float inv = 1.f / (dr*dr + di*di);
    Ar = ((1.f + hr)*dr + hi*di) * inv;
    Ai = (hi*dr - (1.f + hr)*di) * inv;
    sr = dt * dr * inv;
    si = -dt * di * inv;
}

// ============================================================
// K1: gemm1 (V = x @ B^T, 128x128 tile) + chunk-local scan finals.
// Frag maps (verified m89/m91): A[m=lane&15][k=q*8+j], B[n=lane&15][k=q*8+j];
// C/D: col=lane&15, row=q*4+reg.
// ============================================================
__global__ __launch_bounds__(256) void k1(const float* __restrict__ X,
                                          const float* __restrict__ Bw,
                                          const float* __restrict__ llr,
                                          const float* __restrict__ li,
                                          const float* __restrict__ ldt,
                                          __hip_bfloat16* __restrict__ V,
                                          float* __restrict__ finr,
                                          float* __restrict__ fini) {
    __shared__ bf16x8 lds_a[1024];                         // 16KB
    __shared__ bf16x8 lds_b[1024];                         // 16KB
    __shared__ __align__(16) __hip_bfloat16 vt[128][128];  // 32KB V tile
    int t = threadIdx.x;
    int w = t >> 6, lane = t & 63;
    int q = lane >> 4, r = lane & 15;
    int Nblk = blockIdx.x;           // 0..1 (adjacent blocks share X rows -> L2)
    int Mblk = blockIdx.y;           // 0..255
    int wmt = (w & 1) * 4;
    int wnt = (w >> 1) * 4;
    f32x4 acc[4][4] = {};

    for (int kk = 0; kk < 4; ++kk) {
        int k0 = kk * 64;
        #pragma unroll
        for (int s = 0; s < 4; ++s) {
            int f    = s * 256 + t;
            int tile = f >> 6;            // 0..15: mt*2+kb
            int ls   = f & 63;
            int mt   = tile >> 1, kb = tile & 1;
            int qq   = ls >> 4, rr = ls & 15;
            int col  = k0 + kb * 32 + qq * 8;
            const f32x4* pa = (const f32x4*)(X  + (size_t)(Mblk*128 + mt*16 + rr) * 256 + col);
            const f32x4* pb = (const f32x4*)(Bw + (size_t)(Nblk*128 + mt*16 + rr) * 256 + col);
            lds_a[f] = cvt8(pa[0], pa[1]);
            lds_b[f] = cvt8(pb[0], pb[1]);
        }
        __syncthreads();
        #pragma unroll
        for (int kb = 0; kb < 2; ++kb) {
            bf16x8 af[4], bfr[4];
            #pragma unroll
            for (int i = 0; i < 4; ++i) {
                af[i]  = lds_a[((wmt + i)*2 + kb)*64 + lane];
                bfr[i] = lds_b[((wnt + i)*2 + kb)*64 + lane];
            }
            #pragma unroll
            for (int mt = 0; mt < 4; ++mt)
                #pragma unroll
                for (int nt = 0; nt < 4; ++nt)
                    acc[mt][nt] = __builtin_amdgcn_mfma_f32_16x16x32_bf16(
                        af[mt], bfr[nt], acc[mt][nt], 0, 0, 0);
        }
        __syncthreads();
    }
    // epilogue -> LDS V tile (one-time 2B scatter)
    #pragma unroll
    for (int mt = 0; mt < 4; ++mt)
        #pragma unroll
        for (int nt = 0; nt < 4; ++nt)
            #pragma unroll
            for (int reg = 0; reg < 4; ++reg)
                vt[(wmt+mt)*16 + q*4 + reg][(wnt+nt)*16 + r] =
                    __float2bfloat16(acc[mt][nt][reg]);
    __syncthreads();

    int m0 = Mblk * 128;
    // vectorized global V store from LDS
    #pragma unroll
    for (int jj = 0; jj < 8; ++jj) {
        int s  = t + 256 * jj;
        int rl = s >> 4, cv = s & 15;
        u32x4 val = *(const u32x4*)&vt[rl][cv*8];
        *(u32x4*)(V + (size_t)(m0 + rl) * NN + Nblk*128 + cv*8) = val;
    }
    // chunk-local scan from LDS -> finals
    int n_loc = t & 127, n = Nblk*128 + n_loc;
    float Ar, Ai, sr, si;
    ssm_consts(llr, li, ldt, n, Ar, Ai, sr, si);
    int b = m0 >> 12, cbase = (m0 & 4095) >> 5;
    #pragma unroll
    for (int half = 0; half < 2; ++half) {
        int ch = (t >> 7) + half*2;           // 0..3
        float hr = 0.f, hi = 0.f;
        #pragma unroll 8
        for (int i = 0; i < CHUNK; ++i) {
            float v = __bfloat162float(vt[ch*32 + i][n_loc]);
            float tr = fmaf(Ar, hr, fmaf(-Ai, hi, sr * v));
            float ti = fmaf(Ar, hi, fmaf( Ai, hr, si * v));
            hr = tr; hi = ti;
        }
        int f = (b * NCH + cbase + ch) * NN + n;
        finr[f] = hr; fini[f] = hi;
    }
}

// ============================================================
// K2: blocks 0..7  : cross-chunk carry scan (P = A^32)
//     blocks 8..23 : pack [Cr | -Ci] fp32 -> bf16 MFMA-B-fragment order
// ============================================================
__global__ __launch_bounds__(256) void k2(const float* __restrict__ llr,
                                          const float* __restrict__ li,
                                          const float* __restrict__ ldt,
                                          const float* __restrict__ Cr,
                                          const float* __restrict__ Ci,
                                          float* __restrict__ wsf,
                                          u32x4* __restrict__ Cpack) {
    int t = threadIdx.x;
    if (blockIdx.x < 8) {
        int n = t, b = blockIdx.x;
        float Ar, Ai, sr_, si_;
        ssm_consts(llr, li, ldt, n, Ar, Ai, sr_, si_);
        float pr = Ar, pi = Ai;
        #pragma unroll
        for (int i = 0; i < 5; ++i) { float tt = pr*pr - pi*pi; pi = 2.f*pr*pi; pr = tt; }
        float cr = 0.f, ci = 0.f;
        #pragma unroll 4
        for (int c = 0; c < NCH; ++c) {
            int f = (b * NCH + c) * NN + n;
            wsf[WS_CARR + f] = cr; wsf[WS_CARI + f] = ci;
            float fr = wsf[WS_FINR + f], fi = wsf[WS_FINI + f];
            float tr = fmaf(pr, cr, fmaf(-pi, ci, fr));
            float ti = fmaf(pr, ci, fmaf( pi, cr, fi));
            cr = tr; ci = ti;
        }
    } else {
        int ks = blockIdx.x - 8;                 // 0..15 (virtual k-step)
        const float* src = (ks < 8) ? Cr : Ci;
        float sign = (ks < 8) ? 1.f : -1.f;
        #pragma unroll
        for (int jj = 0; jj < 4; ++jj) {
            int s = t + 256 * jj;                // slot within this ks: ot*64+lane
            int ot = s >> 6, lane = s & 63;
            int o  = ot*16 + (lane & 15);
            int kb = (ks & 7)*32 + (lane >> 4)*8;
            bf16x8 v;
            #pragma unroll
            for (int e = 0; e < 8; ++e) v[e] = f2b(sign * src[o*256 + kb + e]);
            Cpack[(ks*16 + ot)*64 + lane] = __builtin_bit_cast(u32x4, v);
        }
    }
}

// ============================================================
// K3: scan replay (with carries) -> h in XOR-swizzled LDS -> out = [hr|hi]@Cpack^T
// 64 rows/block, 512 threads (8 waves), 64KB LDS -> 2 blocks/CU.
// ============================================================
__global__ __launch_bounds__(512) void k3(const __hip_bfloat16* __restrict__ V,
                                          const float* __restrict__ llr,
                                          const float* __restrict__ li,
                                          const float* __restrict__ ldt,
                                          const float* __restrict__ carr,
                                          const float* __restrict__ cari,
                                          const u32x4* __restrict__ Cpack,
                                          float* __restrict__ out) {
    __shared__ __align__(16) char hlds[65536];   // hr @0, hi @32768
    int t = threadIdx.x;
    int m0 = blockIdx.x * 64;
    int b = m0 >> 12, cbase = (m0 & 4095) >> 5;
    {   // ---- scan phase: one (n, chunk) item per thread ----
        int n = t & 255, ch = t >> 8;
        float Ar, Ai, sr, si;
        ssm_consts(llr, li, ldt, n, Ar, Ai, sr, si);
        int f = (b * NCH + cbase + ch) * NN + n;
        float hr = carr[f], hi = cari[f];
        int oct = n >> 3, j = n & 7;
        const __hip_bfloat16* vp = V + (size_t)(m0 + ch*32) * NN + n;
        #pragma unroll 8
        for (int i = 0; i < CHUNK; ++i) {
            float v = __bfloat162float(vp[i * NN]);
            float tr = fmaf(Ar, hr, fmaf(-Ai, hi, sr * v));
            float ti = fmaf(Ar, hi, fmaf( Ai, hr, si * v));
            hr = tr; hi = ti;
            int ml   = ch*32 + i;
            int octp = oct ^ (ml & 31);          // XOR swizzle
            int off  = ((ml*32 + octp) << 4) + (j << 1);
            *(__hip_bfloat16*)(hlds + off)         = __float2bfloat16(hr);
            *(__hip_bfloat16*)(hlds + 32768 + off) = __float2bfloat16(hi);
        }
    }
    __syncthreads();
    // ---- GEMM phase: out[64 x 256], virtual K=512 ----
    int w = t >> 6, lane = t & 63, q = lane >> 4, r = lane & 15;
    f32x4 acc[4][2] = {};
    #pragma unroll
    for (int ks = 0; ks < 16; ++ks) {
        int base = (ks < 8) ? 0 : 32768;
        int kin  = ks & 7;
        bf16x8 af[4];
        #pragma unroll
        for (int mt = 0; mt < 4; ++mt) {
            int ml   = mt*16 + r;
            int octp = (kin*4 + q) ^ (ml & 31);
            af[mt] = *(const bf16x8*)(hlds + base + ((ml*32 + octp) << 4));
        }
        #pragma unroll
        for (int u = 0; u < 2; ++u) {
            bf16x8 bf_ = __builtin_bit_cast(bf16x8, Cpack[(ks*16 + w*2 + u)*64 + lane]);
            #pragma unroll
            for (int mt = 0; mt < 4; ++mt)
                acc[mt][u] = __builtin_amdgcn_mfma_f32_16x16x32_bf16(
                    af[mt], bf_, acc[mt][u], 0, 0, 0);
        }
    }
    #pragma unroll
    for (int mt = 0; mt < 4; ++mt)
        #pragma unroll
        for (int u = 0; u < 2; ++u)
            #pragma unroll
            for (int reg = 0; reg < 4; ++reg)
                out[(size_t)(m0 + mt*16 + q*4 + reg) * NN + (w*2 + u)*16 + r] =
                    acc[mt][u][reg];
}

extern "C" void kernel_launch(void* const* d_in, const int* in_sizes, int n_in,
                              void* d_out, int out_size, void* d_ws, size_t ws_size,
                              hipStream_t stream) {
    const float* x   = (const float*)d_in[0];
    const float* llr = (const float*)d_in[1];
    const float* li  = (const float*)d_in[2];
    const float* ldt = (const float*)d_in[3];
    const float* Bw  = (const float*)d_in[4];
    const float* Cr  = (const float*)d_in[5];
    const float* Ci  = (const float*)d_in[6];

    float* wsf = (float*)d_ws;
    char*  wsb = (char*)d_ws;
    __hip_bfloat16* V = (__hip_bfloat16*)(wsb + WS_V_BYTE);
    u32x4* Cpack      = (u32x4*)(wsb + WS_CP_BYTE);

    k1<<<dim3(2, 256), 256, 0, stream>>>(x, Bw, llr, li, ldt, V,
                                         wsf + WS_FINR, wsf + WS_FINI);
    k2<<<24, 256, 0, stream>>>(llr, li, ldt, Cr, Ci, wsf, Cpack);
    k3<<<512, 512, 0, stream>>>(V, llr, li, ldt,
                                wsf + WS_CARR, wsf + WS_CARI, Cpack, (float*)d_out);
}

// Round 5
// 135.204 us; speedup vs baseline: 2.2736x; 1.0241x over previous
//
#include <hip/hip_runtime.h>
#include <hip/hip_bf16.h>

// ---------- problem sizes (fixed by setup_inputs) ----------
#define BB 8
#define SS 4096
#define NN 256      // d_state = d_input = d_output
#define MM (BB*SS)  // 32768 rows
#define CHUNK 32
#define NCH (SS/CHUNK)  // 128 chunks per batch

// ---------- ws layout (bytes) ----------
#define WS_FINR_B  ((size_t)0)            // BB*NCH*NN fp32 = 1 MB
#define WS_FINI_B  ((size_t)1  << 20)
#define WS_HLR_B   ((size_t)2  << 20)     // 16 MB bf16
#define WS_HLI_B   ((size_t)18 << 20)     // 16 MB bf16
#define WS_CP_B    ((size_t)34 << 20)     // Cpack 256 KB

typedef __bf16 bf16_t;
typedef bf16_t bf16x8 __attribute__((ext_vector_type(8)));
typedef float  f32x4  __attribute__((ext_vector_type(4)));
typedef unsigned int u32x4 __attribute__((ext_vector_type(4)));

__device__ inline bf16_t f2b(float f) {
    __hip_bfloat16 h = __float2bfloat16(f);
    return __builtin_bit_cast(bf16_t, h);
}
__device__ inline float b2f(bf16_t v) {
    unsigned u = (unsigned)__builtin_bit_cast(unsigned short, v) << 16;
    return __builtin_bit_cast(float, u);
}
__device__ inline float b2f_lo(unsigned v) {
    unsigned u = v << 16; return __builtin_bit_cast(float, u);
}
__device__ inline float b2f_hi(unsigned v) {
    unsigned u = v & 0xffff0000u; return __builtin_bit_cast(float, u);
}
__device__ inline unsigned pack2(float lo, float hi) {
    unsigned a = (unsigned)__builtin_bit_cast(unsigned short, f2b(lo));
    unsigned b = (unsigned)__builtin_bit_cast(unsigned short, f2b(hi));
    return a | (b << 16);
}
__device__ inline bf16x8 cvt8(f32x4 a, f32x4 b) {
    bf16x8 o;
    o[0]=f2b(a[0]); o[1]=f2b(a[1]); o[2]=f2b(a[2]); o[3]=f2b(a[3]);
    o[4]=f2b(b[0]); o[5]=f2b(b[1]); o[6]=f2b(b[2]); o[7]=f2b(b[3]);
    return o;
}

// bilinear-discretization constants for state n (~30 VALU, recomputed per block)
__device__ inline void ssm_consts(const float* llr, const float* li, const float* ldt,
                                  int n, float& Ar, float& Ai, float& sr, float& si) {
    float lr = -expf(llr[n]);
    float im = li[n];
    float dt = expf(ldt[n]);
    dt = fminf(fmaxf(dt, 0.005f), 0.1f);
    float hr = 0.5f * dt * lr, hi = 0.5f * dt * im;
    float dr = 1.f - hr, di = -hi;
    float inv = 1.f / (dr*dr + di*di);
    Ar = ((1.f + hr)*dr + hi*di) * inv;
    Ai = (hi*dr - (1.f + hr)*di) * inv;
    sr = dt * dr * inv;
    si = -dt * di * inv;
}

// ============================================================
// K1 (blocks 0..511): gemm1 (V = x@B^T, 128x128 tile) + chunk-local scan
//   -> stores h_local (bf16) + chunk finals (fp32).  Blocks 512..527: Cpack.
// Frag maps (verified m89/m91): A[m=lane&15][k=q*8+j], B[n=lane&15][k=q*8+j];
// C/D: col=lane&15, row=q*4+reg.
// ============================================================
__global__ __launch_bounds__(256, 2) void k1(const float* __restrict__ X,
                                             const float* __restrict__ Bw,
                                             const float* __restrict__ llr,
                                             const float* __restrict__ li,
                                             const float* __restrict__ ldt,
                                             const float* __restrict__ Cr,
                                             const float* __restrict__ Ci,
                                             __hip_bfloat16* __restrict__ HLR,
                                             __hip_bfloat16* __restrict__ HLI,
                                             float* __restrict__ finr,
                                             float* __restrict__ fini,
                                             u32x4* __restrict__ Cpack) {
    __shared__ __align__(16) char smem[65536];
    bf16x8* lds_a = (bf16x8*)smem;                   // 16 KB
    bf16x8* lds_b = (bf16x8*)(smem + 16384);         // 16 KB
    __hip_bfloat16 (*vt)[128]  = (__hip_bfloat16(*)[128])(smem + 32768); // 32 KB (V, then hr in-place)
    __hip_bfloat16 (*hit)[128] = (__hip_bfloat16(*)[128])smem;           // aliases lds_a/b after MFMA

    int t = threadIdx.x;
    int bid = blockIdx.x;
    if (bid >= 512) {   // ---- Cpack: [Cr | -Ci] fp32 -> bf16 B-fragment order ----
        int ks = bid - 512;                  // 0..15 virtual k-step
        const float* src = (ks < 8) ? Cr : Ci;
        float sign = (ks < 8) ? 1.f : -1.f;
        #pragma unroll
        for (int jj = 0; jj < 4; ++jj) {
            int s = t + 256 * jj;
            int ot = s >> 6, lane = s & 63;
            int o  = ot*16 + (lane & 15);
            int kb = (ks & 7)*32 + (lane >> 4)*8;
            bf16x8 v;
            #pragma unroll
            for (int e = 0; e < 8; ++e) v[e] = f2b(sign * src[o*256 + kb + e]);
            Cpack[(ks*16 + ot)*64 + lane] = __builtin_bit_cast(u32x4, v);
        }
        return;
    }

    int w = t >> 6, lane = t & 63;
    int q = lane >> 4, r = lane & 15;
    int Nblk = bid & 1, Mblk = bid >> 1;
    int wmt = (w & 1) * 4;
    int wnt = (w >> 1) * 4;
    f32x4 acc[4][4] = {};

    for (int kk = 0; kk < 4; ++kk) {
        int k0 = kk * 64;
        #pragma unroll
        for (int s = 0; s < 4; ++s) {
            int f    = s * 256 + t;
            int tile = f >> 6;            // mt*2+kb
            int ls   = f & 63;
            int mt   = tile >> 1, kb = tile & 1;
            int qq   = ls >> 4, rr = ls & 15;
            int col  = k0 + kb * 32 + qq * 8;
            const f32x4* pa = (const f32x4*)(X  + (size_t)(Mblk*128 + mt*16 + rr) * 256 + col);
            const f32x4* pb = (const f32x4*)(Bw + (size_t)(Nblk*128 + mt*16 + rr) * 256 + col);
            lds_a[f] = cvt8(pa[0], pa[1]);
            lds_b[f] = cvt8(pb[0], pb[1]);
        }
        __syncthreads();
        #pragma unroll
        for (int kb = 0; kb < 2; ++kb) {
            bf16x8 af[4], bfr[4];
            #pragma unroll
            for (int i = 0; i < 4; ++i) {
                af[i]  = lds_a[((wmt + i)*2 + kb)*64 + lane];
                bfr[i] = lds_b[((wnt + i)*2 + kb)*64 + lane];
            }
            #pragma unroll
            for (int mt = 0; mt < 4; ++mt)
                #pragma unroll
                for (int nt = 0; nt < 4; ++nt)
                    acc[mt][nt] = __builtin_amdgcn_mfma_f32_16x16x32_bf16(
                        af[mt], bfr[nt], acc[mt][nt], 0, 0, 0);
        }
        __syncthreads();
    }
    // epilogue: V tile -> LDS
    #pragma unroll
    for (int mt = 0; mt < 4; ++mt)
        #pragma unroll
        for (int nt = 0; nt < 4; ++nt)
            #pragma unroll
            for (int reg = 0; reg < 4; ++reg)
                vt[(wmt+mt)*16 + q*4 + reg][(wnt+nt)*16 + r] =
                    __float2bfloat16(acc[mt][nt][reg]);
    __syncthreads();

    int m0 = Mblk * 128;
    int b = m0 >> 12, cbase = (m0 & 4095) >> 5;
    // chunk-local scan: wave = chunk, thread handles 2 adjacent states
    {
        int p = t & 63, ch = t >> 6;           // ch = wave id (4 chunks of 32 rows)
        int n0 = Nblk*128 + p*2;
        float Ar0,Ai0,sr0,si0, Ar1,Ai1,sr1,si1;
        ssm_consts(llr, li, ldt, n0,   Ar0, Ai0, sr0, si0);
        ssm_consts(llr, li, ldt, n0+1, Ar1, Ai1, sr1, si1);
        float hr0=0.f, hi0=0.f, hr1=0.f, hi1=0.f;
        #pragma unroll 8
        for (int i = 0; i < CHUNK; ++i) {
            int row = ch*32 + i;
            unsigned vv = *(unsigned*)&vt[row][p*2];
            float v0 = b2f_lo(vv), v1 = b2f_hi(vv);
            float t0r = fmaf(Ar0, hr0, fmaf(-Ai0, hi0, sr0 * v0));
            float t0i = fmaf(Ar0, hi0, fmaf( Ai0, hr0, si0 * v0));
            float t1r = fmaf(Ar1, hr1, fmaf(-Ai1, hi1, sr1 * v1));
            float t1i = fmaf(Ar1, hi1, fmaf( Ai1, hr1, si1 * v1));
            hr0=t0r; hi0=t0i; hr1=t1r; hi1=t1i;
            *(unsigned*)&vt[row][p*2]  = pack2(hr0, hr1);
            *(unsigned*)&hit[row][p*2] = pack2(hi0, hi1);
        }
        int f = (b * NCH + cbase + ch) * NN + n0;
        finr[f] = hr0; finr[f+1] = hr1;
        fini[f] = hi0; fini[f+1] = hi1;
    }
    __syncthreads();
    // vectorized h_local stores
    #pragma unroll
    for (int jj = 0; jj < 8; ++jj) {
        int s  = t + 256 * jj;
        int rl = s >> 4, cv = s & 15;
        *(u32x4*)(HLR + (size_t)(m0 + rl) * NN + Nblk*128 + cv*8) = *(const u32x4*)&vt[rl][cv*8];
        *(u32x4*)(HLI + (size_t)(m0 + rl) * NN + Nblk*128 + cv*8) = *(const u32x4*)&hit[rl][cv*8];
    }
}

// ============================================================
// K3: carry prefix (registers) -> G=A^(i+1)*carry scatter to swizzled LDS
//     -> vectorized h_local add -> GEMM out = [hr|hi] @ Cpack^T.
// 64 rows/block, 512 threads, 64 KB LDS -> 2 blocks/CU.
// ============================================================
__global__ __launch_bounds__(512, 4) void k3(const __hip_bfloat16* __restrict__ HLR,
                                             const __hip_bfloat16* __restrict__ HLI,
                                             const float* __restrict__ finr,
                                             const float* __restrict__ fini,
                                             const float* __restrict__ llr,
                                             const float* __restrict__ li,
                                             const float* __restrict__ ldt,
                                             const u32x4* __restrict__ Cpack,
                                             float* __restrict__ out) {
    __shared__ __align__(16) char hlds[65536];   // hr @0, hi @32768
    int t = threadIdx.x;
    int m0 = blockIdx.x * 64;
    int b = m0 >> 12, cbase = (m0 & 4095) >> 5;

    {   // ---- phases A-C1: per-(n, chunk) in registers ----
        int n = t & 255, d = t >> 8;
        float Ar, Ai, sr_, si_;
        ssm_consts(llr, li, ldt, n, Ar, Ai, sr_, si_);
        float Pr = Ar, Pi = Ai;
        #pragma unroll
        for (int i = 0; i < 5; ++i) { float tt = Pr*Pr - Pi*Pi; Pi = 2.f*Pr*Pi; Pr = tt; }
        // carry = prefix over chunk finals of this batch
        float cr = 0.f, ci = 0.f;
        int ce = cbase + d;
        #pragma unroll 4
        for (int j = 0; j < ce; ++j) {
            int f = (b * NCH + j) * NN + n;
            float fr = finr[f], fi = fini[f];
            float tr = fmaf(Pr, cr, fmaf(-Pi, ci, fr));
            float ti = fmaf(Pr, ci, fmaf( Pi, cr, fi));
            cr = tr; ci = ti;
        }
        // G_i = A^(i+1) * carry, scattered to swizzled LDS (bf16)
        float gr = Ar*cr - Ai*ci;
        float gi = Ar*ci + Ai*cr;
        int oct = n >> 3, j2 = (n & 7) * 2;
        #pragma unroll 8
        for (int i = 0; i < CHUNK; ++i) {
            int row  = d*32 + i;
            int octp = oct ^ (row & 31);
            int off  = ((row*32 + octp) << 4) + j2;
            *(__hip_bfloat16*)(hlds + off)         = __float2bfloat16(gr);
            *(__hip_bfloat16*)(hlds + 32768 + off) = __float2bfloat16(gi);
            float tg = Ar*gr - Ai*gi;
            gi = fmaf(Ar, gi, Ai*gr);
            gr = tg;
        }
    }
    __syncthreads();
    // ---- phase C2: h = h_local + G (all b128, coalesced) ----
    #pragma unroll
    for (int jj = 0; jj < 4; ++jj) {
        int s = t + 512*jj;
        int row = s >> 5, oct = s & 31;
        int octp = oct ^ (row & 31);
        char* ptr_r = hlds + ((row*32 + octp) << 4);
        char* ptr_i = ptr_r + 32768;
        u32x4 hru = *(const u32x4*)(HLR + (size_t)(m0 + row) * NN + oct*8);
        u32x4 hiu = *(const u32x4*)(HLI + (size_t)(m0 + row) * NN + oct*8);
        bf16x8 hl_r = __builtin_bit_cast(bf16x8, hru);
        bf16x8 hl_i = __builtin_bit_cast(bf16x8, hiu);
        bf16x8 g_r = *(const bf16x8*)ptr_r;
        bf16x8 g_i = *(const bf16x8*)ptr_i;
        bf16x8 o_r, o_i;
        #pragma unroll
        for (int e = 0; e < 8; ++e) {
            o_r[e] = f2b(b2f(hl_r[e]) + b2f(g_r[e]));
            o_i[e] = f2b(b2f(hl_i[e]) + b2f(g_i[e]));
        }
        *(bf16x8*)ptr_r = o_r;
        *(bf16x8*)ptr_i = o_i;
    }
    __syncthreads();
    // ---- phase D: GEMM out[64 x 256], virtual K=512 ----
    int w = t >> 6, lane = t & 63, q = lane >> 4, r = lane & 15;
    f32x4 acc[4][2] = {};
    #pragma unroll
    for (int ks = 0; ks < 16; ++ks) {
        int base = (ks < 8) ? 0 : 32768;
        int kin  = ks & 7;
        bf16x8 af[4];
        #pragma unroll
        for (int mt = 0; mt < 4; ++mt) {
            int ml   = mt*16 + r;
            int octp = (kin*4 + q) ^ (ml & 31);
            af[mt] = *(const bf16x8*)(hlds + base + ((ml*32 + octp) << 4));
        }
        #pragma unroll
        for (int u = 0; u < 2; ++u) {
            bf16x8 bf_ = __builtin_bit_cast(bf16x8, Cpack[(ks*16 + w*2 + u)*64 + lane]);
            #pragma unroll
            for (int mt = 0; mt < 4; ++mt)
                acc[mt][u] = __builtin_amdgcn_mfma_f32_16x16x32_bf16(
                    af[mt], bf_, acc[mt][u], 0, 0, 0);
        }
    }
    #pragma unroll
    for (int mt = 0; mt < 4; ++mt)
        #pragma unroll
        for (int u = 0; u < 2; ++u)
            #pragma unroll
            for (int reg = 0; reg < 4; ++reg)
                out[(size_t)(m0 + mt*16 + q*4 + reg) * NN + (w*2 + u)*16 + r] =
                    acc[mt][u][reg];
}

extern "C" void kernel_launch(void* const* d_in, const int* in_sizes, int n_in,
                              void* d_out, int out_size, void* d_ws, size_t ws_size,
                              hipStream_t stream) {
    const float* x   = (const float*)d_in[0];
    const float* llr = (const float*)d_in[1];
    const float* li  = (const float*)d_in[2];
    const float* ldt = (const float*)d_in[3];
    const float* Bw  = (const float*)d_in[4];
    const float* Cr  = (const float*)d_in[5];
    const float* Ci  = (const float*)d_in[6];

    char* wsb = (char*)d_ws;
    float* finr = (float*)(wsb + WS_FINR_B);
    float* fini = (float*)(wsb + WS_FINI_B);
    __hip_bfloat16* HLR = (__hip_bfloat16*)(wsb + WS_HLR_B);
    __hip_bfloat16* HLI = (__hip_bfloat16*)(wsb + WS_HLI_B);
    u32x4* Cpack        = (u32x4*)(wsb + WS_CP_B);

    k1<<<528, 256, 0, stream>>>(x, Bw, llr, li, ldt, Cr, Ci,
                                HLR, HLI, finr, fini, Cpack);
    k3<<<512, 512, 0, stream>>>(HLR, HLI, finr, fini, llr, li, ldt,
                                Cpack, (float*)d_out);
}